// Round 15
// baseline (238.701 us; speedup 1.0000x reference)
//
#include <hip/hip_runtime.h>
#include <hip/hip_bf16.h>

#define N_NODES 50000
#define N_EDGES 800000
#define FEAT    128
#define HID     128
#define NCLS    40
#define XPAD    50048            // N rounded up to 64 (GEMM tiles guarded by row checks)

#define RANGE   12500            // nodes per LDS-histogram range (50 KB of u32)
#define NRANGE  4                // 4 * 12500 = 50000
#define NS      32               // edge slices
#define SLICE   (N_EDGES / NS)   // 25000 edges per slice
#define NBLK    49               // scan blocks: ceil(50000/1024)

// ---------------- workspace layout ----------------
static constexpr size_t ALIGNB = 256;
static constexpr size_t aln(size_t x){ return (x + ALIGNB - 1) & ~(ALIGNB - 1); }
static constexpr size_t OFF_ONORM   = 0;
static constexpr size_t OFF_INORM   = OFF_ONORM + aln((size_t)N_NODES * 4);
static constexpr size_t OFF_ROWPTR  = OFF_INORM + aln((size_t)N_NODES * 4);
static constexpr size_t OFF_BSUM    = OFF_ROWPTR + aln((size_t)(N_NODES + 1) * 4);
static constexpr size_t OFF_FLAG    = OFF_BSUM + aln(64 * 4);
static constexpr size_t OFF_WT1     = OFF_FLAG + aln(64 * 4);
static constexpr size_t OFF_WT2     = OFF_WT1 + aln((size_t)128 * 128 * 2);
static constexpr size_t OFF_WT3     = OFF_WT2 + aln((size_t)128 * 128 * 2);
static constexpr size_t OFF_ESRC    = OFF_WT3 + aln((size_t)64 * 128 * 2);
static constexpr size_t OFF_HTMP    = OFF_ESRC + aln((size_t)N_EDGES * 4);
static constexpr size_t OFF_XBUF    = OFF_HTMP + aln((size_t)XPAD * 128 * 2);
// partial histograms alias htmp (dead before GEMM1 writes htmp):
// part[z][r][s][RANGE] = 2*4*32*12500*4 = 12.8 MB <= htmp region
static constexpr size_t OFF_PART    = OFF_HTMP;

// ---------------- helpers ----------------
__device__ __forceinline__ float bflo(unsigned u){
  union { unsigned i; float f; } c; c.i = u << 16; return c.f;
}
__device__ __forceinline__ float bfhi(unsigned u){
  union { unsigned i; float f; } c; c.i = u & 0xffff0000u; return c.f;
}
__device__ __forceinline__ unsigned pkbf(float a, float b){
  union { __hip_bfloat16 h; unsigned short u; } ca, cb;
  ca.h = __float2bfloat16(a); cb.h = __float2bfloat16(b);
  return ((unsigned)cb.u << 16) | (unsigned)ca.u;
}
__device__ __forceinline__ unsigned short bf1(float a){
  union { __hip_bfloat16 h; unsigned short u; } c;
  c.h = __float2bfloat16(a); return c.u;
}

typedef __attribute__((ext_vector_type(8))) short bf16x8;
typedef __attribute__((ext_vector_type(4))) float f32x4;

// ---------------- LDS histogram + folded weight prep + flag init ----------------
// grid = (NS, NRANGE, 2); z selects dst (in-deg) vs src (out-deg).
// Blocks z==0,r==0,s<20 additionally convert W1/W2/W3 -> transposed bf16 wt.
// Block z==1,r==0,s==0 zeroes the k_scan spin flag (device-scope -> MALL).
__global__ __launch_bounds__(1024) void k_hist_lds(const int* __restrict__ src,
                                                   const int* __restrict__ dst,
                                                   unsigned* __restrict__ part,
                                                   unsigned* __restrict__ flag,
                                                   const float* __restrict__ W1,
                                                   const float* __restrict__ W2,
                                                   const float* __restrict__ W3,
                                                   unsigned* __restrict__ wt1,
                                                   unsigned* __restrict__ wt2,
                                                   unsigned* __restrict__ wt3){
  __shared__ unsigned h[RANGE];
  const int s = blockIdx.x, r = blockIdx.y, z = blockIdx.z;
  if (z == 1 && r == 0 && s == 0 && threadIdx.x == 0) atomicExch(flag, 0u);
  if (z == 0 && r == 0 && s < 20){
    int idx = s * 1024 + threadIdx.x;
    const float* W; unsigned* Wt; int WC;
    if (idx < 8192)       { W = W1; Wt = wt1; WC = 128; }
    else if (idx < 16384) { W = W2; Wt = wt2; WC = 128; idx -= 8192; }
    else                  { W = W3; Wt = wt3; WC = 40;  idx -= 16384; }
    int c = idx >> 6, kp = idx & 63;
    float v0 = (c < WC) ? W[(size_t)(2 * kp)     * WC + c] : 0.f;
    float v1 = (c < WC) ? W[(size_t)(2 * kp + 1) * WC + c] : 0.f;
    Wt[idx] = pkbf(v0, v1);
  }
  const int* __restrict__ idxp = z ? src : dst;
  const int lo = r * RANGE;
  for (int i = threadIdx.x; i < RANGE; i += 1024) h[i] = 0;
  __syncthreads();
  const int e0 = s * SLICE;
  for (int e = e0 + threadIdx.x; e < e0 + SLICE; e += 1024){
    int v = idxp[e] - lo;
    if ((unsigned)v < RANGE) atomicAdd(&h[v], 1u);   // LDS atomic
  }
  __syncthreads();
  unsigned* p = part + (((size_t)z * NRANGE + r) * NS + s) * RANGE;
  for (int i = threadIdx.x; i < RANGE; i += 1024) p[i] = h[i];
}

// ---------------- merged scan: norms + local scan -> spin barrier -> offsets + cursors ----------------
// 49 blocks x 1024 (< 256 CUs -> co-resident). Cross-block data (bsum, flag) goes
// through agent-scope atomics (MALL) because per-XCD L2s are non-coherent.
__global__ __launch_bounds__(1024) void k_scan(const unsigned* __restrict__ part_c,
                                               unsigned* __restrict__ part,
                                               int* __restrict__ rowptr,
                                               unsigned* __restrict__ bsum,
                                               unsigned* __restrict__ flag,
                                               float* __restrict__ inorm,
                                               float* __restrict__ onorm){
  __shared__ int wsum[16];
  __shared__ unsigned sboff, stotal;
  const int t = threadIdx.x, lane = t & 63, w = t >> 6;
  const int b = blockIdx.x;
  const int i = b * 1024 + t;

  // ---- phase A: reduce partials -> norms + local block scan ----
  int v = 0;
  if (i < N_NODES){
    int r = i / RANGE, off = i % RANGE;
    const unsigned* pi = part_c + ((size_t)r * NS) * RANGE + off;
    const unsigned* po = part_c + (((size_t)NRANGE + r) * NS) * RANGE + off;
    unsigned si = 0, so = 0;
    #pragma unroll 8
    for (int s = 0; s < NS; ++s){
      si += pi[(size_t)s * RANGE];
      so += po[(size_t)s * RANGE];
    }
    inorm[i] = rsqrtf(fmaxf((float)si, 1.0f));
    onorm[i] = rsqrtf(fmaxf((float)so, 1.0f));
    v = (int)si;
  }
  int x = v;
  #pragma unroll
  for (int off = 1; off < 64; off <<= 1){
    int y = __shfl_up(x, off, 64);
    if (lane >= off) x += y;
  }
  if (lane == 63) wsum[w] = x;
  __syncthreads();
  if (w == 0 && lane < 16){
    int s = wsum[lane];
    #pragma unroll
    for (int off = 1; off < 16; off <<= 1){
      int y = __shfl_up(s, off, 64);
      if (lane >= off) s += y;
    }
    wsum[lane] = s;
  }
  __syncthreads();
  int woff = (w > 0) ? wsum[w - 1] : 0;
  if (i < N_NODES) rowptr[i] = woff + x - v;

  // ---- spin barrier across 49 co-resident blocks ----
  if (t == 0){
    __hip_atomic_store(&bsum[b], (unsigned)wsum[15],
                       __ATOMIC_RELEASE, __HIP_MEMORY_SCOPE_AGENT);
    __threadfence();
    atomicAdd(flag, 1u);                       // device scope (MALL RMW)
    while (__hip_atomic_load(flag, __ATOMIC_ACQUIRE, __HIP_MEMORY_SCOPE_AGENT) < NBLK)
      __builtin_amdgcn_s_sleep(2);
  }
  __syncthreads();

  // ---- phase B: bsum wave-scan + add offsets + transform part into base cursors ----
  if (t < 64){
    unsigned bv = (t < NBLK)
      ? __hip_atomic_load(&bsum[t], __ATOMIC_ACQUIRE, __HIP_MEMORY_SCOPE_AGENT) : 0u;
    int vv = (int)bv, xx = vv;
    #pragma unroll
    for (int off = 1; off < 64; off <<= 1){
      int y = __shfl_up(xx, off, 64);
      if (t >= off) xx += y;
    }
    if (t == b) sboff = (unsigned)(xx - vv);
    if (t == NBLK - 1) stotal = (unsigned)xx;
  }
  __syncthreads();
  if (i < N_NODES){
    int rp = rowptr[i] + (int)sboff;
    rowptr[i] = rp;
    int r = i / RANGE, off = i % RANGE;
    unsigned* p = part + ((size_t)r * NS) * RANGE + off;
    unsigned run = (unsigned)rp;
    #pragma unroll 8
    for (int s = 0; s < NS; ++s){
      unsigned c = p[(size_t)s * RANGE];
      p[(size_t)s * RANGE] = run;
      run += c;
    }
  } else if (i == N_NODES) rowptr[i] = (int)stotal;
}

// ---------------- scatter edges into CSR slots (LDS cursor atomics) ----------------
// grid = (NS, NRANGE)
__global__ __launch_bounds__(1024) void k_scatter_lds(const int* __restrict__ src,
                                                      const int* __restrict__ dst,
                                                      const unsigned* __restrict__ part,
                                                      int* __restrict__ esrc){
  __shared__ unsigned cur[RANGE];
  const int s = blockIdx.x, r = blockIdx.y;
  const int lo = r * RANGE;
  const unsigned* p = part + ((size_t)r * NS + s) * RANGE;
  for (int i = threadIdx.x; i < RANGE; i += 1024) cur[i] = p[i];
  __syncthreads();
  const int e0 = s * SLICE;
  for (int e = e0 + threadIdx.x; e < e0 + SLICE; e += 1024){
    int v = dst[e] - lo;
    if ((unsigned)v < RANGE){
      unsigned pos = atomicAdd(&cur[v], 1u);          // LDS atomic
      esrc[pos] = src[e];
    }
  }
}

// ---------------- MFMA GEMM: out[r][c] = bf16( onorm[r] * sum_k X[r][k] * W[k][c] ) ----------------
// X: bf16 [XPAD][128] or fp32 [N][128] (IN_F32: converted in-register, row clamped).
// Wt: bf16 [CT*16][128] (c-major). Block = 4 waves x 64 rows.
template<int CT, int WCOUT, int OUTC, bool IN_F32>
__global__ __launch_bounds__(256) void k_gemm_mfma(const void* __restrict__ xin,
                                                   const unsigned short* __restrict__ wt,
                                                   const float* __restrict__ onorm,
                                                   unsigned short* __restrict__ outb){
  __shared__ unsigned short Wl[CT * 16][136];
  const int t = threadIdx.x;
  const int lane = t & 63;
  const int w = t >> 6;
  const int ln15 = lane & 15;
  const int quad = lane >> 4;

  {
    const uint4* w4 = (const uint4*)wt;      // 16 uint4 per 128-bf16 row
    #pragma unroll
    for (int i = 0; i < CT; ++i){
      int idx = t + i * 256;
      int row = idx >> 4, q = idx & 15;
      *(uint4*)&Wl[row][q * 8] = w4[idx];
    }
  }
  __syncthreads();

  f32x4 acc[CT];
  #pragma unroll
  for (int ct = 0; ct < CT; ++ct) acc[ct] = (f32x4){0.f, 0.f, 0.f, 0.f};

  const int xr = min(blockIdx.x * 64 + w * 16 + ln15, N_NODES - 1);  // clamp: padded rows unused
  #pragma unroll
  for (int kp = 0; kp < 4; ++kp){
    bf16x8 a;
    if (IN_F32){
      const float4* x4 = (const float4*)xin + (size_t)xr * 32;
      float4 p0 = x4[kp * 8 + quad * 2];
      float4 p1 = x4[kp * 8 + quad * 2 + 1];
      union { bf16x8 v; unsigned u[4]; } ua;
      ua.u[0] = pkbf(p0.x, p0.y); ua.u[1] = pkbf(p0.z, p0.w);
      ua.u[2] = pkbf(p1.x, p1.y); ua.u[3] = pkbf(p1.z, p1.w);
      a = ua.v;
    } else {
      const unsigned short* xrow = (const unsigned short*)xin + (size_t)xr * 128;
      a = *(const bf16x8*)(xrow + kp * 32 + quad * 8);
    }
    #pragma unroll
    for (int ct = 0; ct < CT; ++ct){
      bf16x8 b = *(const bf16x8*)&Wl[ct * 16 + ln15][kp * 32 + quad * 8];
      acc[ct] = __builtin_amdgcn_mfma_f32_16x16x32_bf16(a, b, acc[ct], 0, 0, 0);
    }
  }

  // epilogue: C/D layout col=lane&15, row=quad*4+reg
  const int rowbase = blockIdx.x * 64 + w * 16 + quad * 4;
  float o[4];
  #pragma unroll
  for (int j = 0; j < 4; ++j){
    int r = rowbase + j;
    o[j] = (r < N_NODES) ? onorm[r] : 0.f;
  }
  #pragma unroll
  for (int ct = 0; ct < CT; ++ct){
    int col = ct * 16 + ln15;
    if (WCOUT < CT * 16 && col >= WCOUT) continue;
    #pragma unroll
    for (int j = 0; j < 4; ++j){
      int r = rowbase + j;
      if (r < N_NODES)
        outb[(size_t)r * OUTC + col] = bf1(acc[ct][j] * o[j]);
    }
  }
}

// ---------------- wave-per-node bf16 gather-aggregate (128-wide) ----------------
// htmp rows are 128 bf16 (64 u32); lane l owns cols {2l, 2l+1}.
template<bool OUTBF>
__global__ __launch_bounds__(256) void k_agg(const unsigned* __restrict__ htmp,
                                             const int* __restrict__ rowptr,
                                             const int* __restrict__ esrc,
                                             const float* __restrict__ inorm,
                                             const float* __restrict__ bias,
                                             void* __restrict__ outv){
  const int wave = threadIdx.x >> 6;
  const int lane = threadIdx.x & 63;
  const int node = blockIdx.x * 4 + wave;
  if (node >= N_NODES) return;
  const int start = rowptr[node], end = rowptr[node + 1];
  float aL[4] = {0.f, 0.f, 0.f, 0.f};
  float aH[4] = {0.f, 0.f, 0.f, 0.f};
  for (int e0 = start; e0 < end; e0 += 64){
    const int n = min(64, end - e0);
    int el = (lane < n) ? esrc[e0 + lane] : 0;
    int j = 0;
    for (; j + 8 <= n; j += 8){
      int ss[8];
      #pragma unroll
      for (int q = 0; q < 8; ++q) ss[q] = __shfl(el, j + q);
      unsigned uu[8];
      #pragma unroll
      for (int q = 0; q < 8; ++q) uu[q] = htmp[(size_t)ss[q] * 64 + lane];
      #pragma unroll
      for (int q = 0; q < 8; ++q){ aL[q & 3] += bflo(uu[q]); aH[q & 3] += bfhi(uu[q]); }
    }
    for (; j + 4 <= n; j += 4){
      int ss[4];
      #pragma unroll
      for (int q = 0; q < 4; ++q) ss[q] = __shfl(el, j + q);
      unsigned uu[4];
      #pragma unroll
      for (int q = 0; q < 4; ++q) uu[q] = htmp[(size_t)ss[q] * 64 + lane];
      #pragma unroll
      for (int q = 0; q < 4; ++q){ aL[q] += bflo(uu[q]); aH[q] += bfhi(uu[q]); }
    }
    for (; j < n; ++j){
      int s0 = __shfl(el, j);
      unsigned u0 = htmp[(size_t)s0 * 64 + lane];
      aL[0] += bflo(u0); aH[0] += bfhi(u0);
    }
  }
  float sc = inorm[node];
  float y0 = ((aL[0] + aL[1]) + (aL[2] + aL[3])) * sc + bias[2 * lane];
  float y1 = ((aH[0] + aH[1]) + (aH[2] + aH[3])) * sc + bias[2 * lane + 1];
  y0 = fmaxf(y0, 0.f); y1 = fmaxf(y1, 0.f);
  if (OUTBF){
    ((unsigned*)outv)[(size_t)node * 64 + lane] = pkbf(y0, y1);
  } else {
    float2 v; v.x = y0; v.y = y1;
    *(float2*)&((float*)outv)[(size_t)node * 128 + 2 * lane] = v;
  }
}

// ---------------- packed final aggregate: 3 nodes per wave (20 lanes each, 40-wide rows) ----------------
// htmp rows are 40 bf16 = 20 u32; sub-lane sl owns cols {2sl, 2sl+1}.
__global__ __launch_bounds__(256) void k_agg3(const unsigned* __restrict__ htmp,
                                              const int* __restrict__ rowptr,
                                              const int* __restrict__ esrc,
                                              const float* __restrict__ inorm,
                                              const float* __restrict__ bias,
                                              float* __restrict__ outf){
  const int wave = threadIdx.x >> 6;
  const int lane = threadIdx.x & 63;
  const int sg = lane / 20;               // subgroup 0..2 (3 = idle lanes 60-63)
  const int sl = lane % 20;
  const int node = blockIdx.x * 12 + wave * 3 + sg;
  const bool act = (sg < 3) && (node < N_NODES);
  const int start = act ? rowptr[node] : 0;
  const int end   = act ? rowptr[node + 1] : 0;
  float aL[4] = {0.f, 0.f, 0.f, 0.f};
  float aH[4] = {0.f, 0.f, 0.f, 0.f};
  for (int e0 = start; e0 < end; e0 += 20){
    const int n = min(20, end - e0);
    int el = (sl < n) ? esrc[e0 + sl] : 0;
    int j = 0;
    for (; j + 4 <= n; j += 4){
      int ss[4];
      #pragma unroll
      for (int q = 0; q < 4; ++q) ss[q] = __shfl(el, sg * 20 + j + q);
      unsigned uu[4];
      #pragma unroll
      for (int q = 0; q < 4; ++q) uu[q] = htmp[(size_t)ss[q] * 20 + sl];
      #pragma unroll
      for (int q = 0; q < 4; ++q){ aL[q] += bflo(uu[q]); aH[q] += bfhi(uu[q]); }
    }
    for (; j < n; ++j){
      int s0 = __shfl(el, sg * 20 + j);
      unsigned u0 = htmp[(size_t)s0 * 20 + sl];
      aL[0] += bflo(u0); aH[0] += bfhi(u0);
    }
  }
  if (act){
    float sc = inorm[node];
    float y0 = ((aL[0] + aL[1]) + (aL[2] + aL[3])) * sc + bias[2 * sl];
    float y1 = ((aH[0] + aH[1]) + (aH[2] + aH[3])) * sc + bias[2 * sl + 1];
    float2 v; v.x = y0; v.y = y1;
    *(float2*)&outf[(size_t)node * 40 + 2 * sl] = v;
  }
}

// ---------------- launch ----------------
extern "C" void kernel_launch(void* const* d_in, const int* in_sizes, int n_in,
                              void* d_out, int out_size, void* d_ws, size_t ws_size,
                              hipStream_t stream){
  const float* feat = (const float*)d_in[0];
  const float* W1   = (const float*)d_in[1];
  const float* b1   = (const float*)d_in[2];
  const float* W2   = (const float*)d_in[3];
  const float* b2   = (const float*)d_in[4];
  const float* W3   = (const float*)d_in[5];
  const float* b3   = (const float*)d_in[6];
  const int* src = (const int*)d_in[7];
  const int* dst = (const int*)d_in[8];
  float* out = (float*)d_out;

  char* ws = (char*)d_ws;
  float*    onorm   = (float*)   (ws + OFF_ONORM);
  float*    inorm   = (float*)   (ws + OFF_INORM);
  int*      rowptr  = (int*)     (ws + OFF_ROWPTR);
  unsigned* bsum    = (unsigned*)(ws + OFF_BSUM);
  unsigned* flag    = (unsigned*)(ws + OFF_FLAG);
  unsigned* wt1     = (unsigned*)(ws + OFF_WT1);
  unsigned* wt2     = (unsigned*)(ws + OFF_WT2);
  unsigned* wt3     = (unsigned*)(ws + OFF_WT3);
  int*      esrc    = (int*)     (ws + OFF_ESRC);
  unsigned short* htmp = (unsigned short*)(ws + OFF_HTMP);
  unsigned short* xbuf = (unsigned short*)(ws + OFF_XBUF);
  unsigned* part    = (unsigned*)(ws + OFF_PART);   // aliases htmp (dead before GEMM1)

  // ---- CSR build (LDS atomics only) + folded weight prep: 3 dispatches ----
  k_hist_lds    <<<dim3(NS, NRANGE, 2), 1024, 0, stream>>>(src, dst, part, flag,
                                                           W1, W2, W3, wt1, wt2, wt3);
  k_scan        <<<NBLK, 1024, 0, stream>>>(part, part, rowptr, bsum, flag, inorm, onorm);
  k_scatter_lds <<<dim3(NS, NRANGE), 1024, 0, stream>>>(src, dst, part, esrc);

  const int GB = XPAD / 64;            // 782
  const int AB = (N_NODES + 3) / 4;
  // layer 1 (fp32 feat read directly, converted in-register)
  k_gemm_mfma<8, 128, 128, true ><<<GB, 256, 0, stream>>>(feat, (unsigned short*)wt1, onorm, htmp);
  k_agg<true ><<<AB, 256, 0, stream>>>((unsigned*)htmp, rowptr, esrc, inorm, b1, xbuf);
  // layer 2
  k_gemm_mfma<8, 128, 128, false><<<GB, 256, 0, stream>>>(xbuf, (unsigned short*)wt2, onorm, htmp);
  k_agg<true ><<<AB, 256, 0, stream>>>((unsigned*)htmp, rowptr, esrc, inorm, b2, xbuf);
  // layer 3 (40 real cols, 64 computed)
  k_gemm_mfma<4, 40, 40, false><<<GB, 256, 0, stream>>>(xbuf, (unsigned short*)wt3, onorm, htmp);
  k_agg3<<<(N_NODES + 11) / 12, 256, 0, stream>>>((unsigned*)htmp, rowptr, esrc, inorm, b3, out);
}

// Round 16
// 233.101 us; speedup vs baseline: 1.0240x; 1.0240x over previous
//
#include <hip/hip_runtime.h>
#include <hip/hip_bf16.h>

#define N_NODES 50000
#define N_EDGES 800000
#define FEAT    128
#define HID     128
#define NCLS    40
#define XPAD    50048            // N rounded up to 64 (GEMM tiles guarded by row checks)

#define RANGE   12500            // nodes per LDS-histogram range (50 KB of u32)
#define NRANGE  4                // 4 * 12500 = 50000
#define NS      32               // edge slices
#define SLICE   (N_EDGES / NS)   // 25000 edges per slice
#define NBLK    49               // scan blocks: ceil(50000/1024)

// ---------------- workspace layout ----------------
static constexpr size_t ALIGNB = 256;
static constexpr size_t aln(size_t x){ return (x + ALIGNB - 1) & ~(ALIGNB - 1); }
static constexpr size_t OFF_ONORM   = 0;
static constexpr size_t OFF_INORM   = OFF_ONORM + aln((size_t)N_NODES * 4);
static constexpr size_t OFF_ROWPTR  = OFF_INORM + aln((size_t)N_NODES * 4);
static constexpr size_t OFF_BSUM    = OFF_ROWPTR + aln((size_t)(N_NODES + 1) * 4);
static constexpr size_t OFF_WT1     = OFF_BSUM + aln(64 * 4);
static constexpr size_t OFF_WT2     = OFF_WT1 + aln((size_t)128 * 128 * 2);
static constexpr size_t OFF_WT3     = OFF_WT2 + aln((size_t)128 * 128 * 2);
static constexpr size_t OFF_ESRC    = OFF_WT3 + aln((size_t)64 * 128 * 2);
static constexpr size_t OFF_HTMP    = OFF_ESRC + aln((size_t)N_EDGES * 4);
static constexpr size_t OFF_XBUF    = OFF_HTMP + aln((size_t)XPAD * 128 * 2);
// partial histograms alias htmp (dead before GEMM1 writes htmp):
// part[z][r][s][RANGE] = 2*4*32*12500*4 = 12.8 MB <= htmp region
static constexpr size_t OFF_PART    = OFF_HTMP;

// ---------------- helpers ----------------
__device__ __forceinline__ float bflo(unsigned u){
  union { unsigned i; float f; } c; c.i = u << 16; return c.f;
}
__device__ __forceinline__ float bfhi(unsigned u){
  union { unsigned i; float f; } c; c.i = u & 0xffff0000u; return c.f;
}
__device__ __forceinline__ unsigned pkbf(float a, float b){
  union { __hip_bfloat16 h; unsigned short u; } ca, cb;
  ca.h = __float2bfloat16(a); cb.h = __float2bfloat16(b);
  return ((unsigned)cb.u << 16) | (unsigned)ca.u;
}
__device__ __forceinline__ unsigned short bf1(float a){
  union { __hip_bfloat16 h; unsigned short u; } c;
  c.h = __float2bfloat16(a); return c.u;
}

typedef __attribute__((ext_vector_type(8))) short bf16x8;
typedef __attribute__((ext_vector_type(4))) float f32x4;

// ---------------- LDS histogram + folded weight prep ----------------
// grid = (NS, NRANGE, 2); z selects dst (in-deg) vs src (out-deg).
// Blocks z==0,r==0,s<20 additionally convert W1/W2/W3 -> transposed bf16 wt.
__global__ __launch_bounds__(1024) void k_hist_lds(const int* __restrict__ src,
                                                   const int* __restrict__ dst,
                                                   unsigned* __restrict__ part,
                                                   const float* __restrict__ W1,
                                                   const float* __restrict__ W2,
                                                   const float* __restrict__ W3,
                                                   unsigned* __restrict__ wt1,
                                                   unsigned* __restrict__ wt2,
                                                   unsigned* __restrict__ wt3){
  __shared__ unsigned h[RANGE];
  const int s = blockIdx.x, r = blockIdx.y, z = blockIdx.z;
  if (z == 0 && r == 0 && s < 20){
    int idx = s * 1024 + threadIdx.x;
    const float* W; unsigned* Wt; int WC;
    if (idx < 8192)       { W = W1; Wt = wt1; WC = 128; }
    else if (idx < 16384) { W = W2; Wt = wt2; WC = 128; idx -= 8192; }
    else                  { W = W3; Wt = wt3; WC = 40;  idx -= 16384; }
    int c = idx >> 6, kp = idx & 63;
    float v0 = (c < WC) ? W[(size_t)(2 * kp)     * WC + c] : 0.f;
    float v1 = (c < WC) ? W[(size_t)(2 * kp + 1) * WC + c] : 0.f;
    Wt[idx] = pkbf(v0, v1);
  }
  const int* __restrict__ idxp = z ? src : dst;
  const int lo = r * RANGE;
  for (int i = threadIdx.x; i < RANGE; i += 1024) h[i] = 0;
  __syncthreads();
  const int e0 = s * SLICE;
  for (int e = e0 + threadIdx.x; e < e0 + SLICE; e += 1024){
    int v = idxp[e] - lo;
    if ((unsigned)v < RANGE) atomicAdd(&h[v], 1u);   // LDS atomic
  }
  __syncthreads();
  unsigned* p = part + (((size_t)z * NRANGE + r) * NS + s) * RANGE;
  for (int i = threadIdx.x; i < RANGE; i += 1024) p[i] = h[i];
}

// ---------------- fused: reduce partials -> norms + local block scan ----------------
__global__ __launch_bounds__(1024) void k_scan1(const unsigned* __restrict__ part,
                                                int* __restrict__ rowptr,
                                                unsigned* __restrict__ bsum,
                                                float* __restrict__ inorm,
                                                float* __restrict__ onorm){
  __shared__ int wsum[16];
  const int t = threadIdx.x, lane = t & 63, w = t >> 6;
  const int i = blockIdx.x * 1024 + t;
  int v = 0;
  if (i < N_NODES){
    int r = i / RANGE, off = i % RANGE;
    const unsigned* pi = part + ((size_t)r * NS) * RANGE + off;
    const unsigned* po = part + (((size_t)NRANGE + r) * NS) * RANGE + off;
    unsigned si = 0, so = 0;
    #pragma unroll 8
    for (int s = 0; s < NS; ++s){
      si += pi[(size_t)s * RANGE];
      so += po[(size_t)s * RANGE];
    }
    inorm[i] = rsqrtf(fmaxf((float)si, 1.0f));
    onorm[i] = rsqrtf(fmaxf((float)so, 1.0f));
    v = (int)si;
  }
  int x = v;
  #pragma unroll
  for (int off = 1; off < 64; off <<= 1){
    int y = __shfl_up(x, off, 64);
    if (lane >= off) x += y;
  }
  if (lane == 63) wsum[w] = x;
  __syncthreads();
  if (w == 0 && lane < 16){
    int s = wsum[lane];
    #pragma unroll
    for (int off = 1; off < 16; off <<= 1){
      int y = __shfl_up(s, off, 64);
      if (lane >= off) s += y;
    }
    wsum[lane] = s;
  }
  __syncthreads();
  int woff = (w > 0) ? wsum[w - 1] : 0;
  if (i < N_NODES) rowptr[i] = woff + x - v;
  if (t == 0) bsum[blockIdx.x] = (unsigned)wsum[15];
}

// ---------------- fused: redundant bsum scan + add offsets + build base cursors ----------------
__global__ __launch_bounds__(1024) void k_scan3(int* __restrict__ rowptr,
                                                const unsigned* __restrict__ bsum,
                                                unsigned* __restrict__ part){
  __shared__ unsigned sboff, stotal;
  const int t = threadIdx.x;
  if (t < 64){
    int v = (t < NBLK) ? (int)bsum[t] : 0;
    int x = v;
    #pragma unroll
    for (int off = 1; off < 64; off <<= 1){
      int y = __shfl_up(x, off, 64);
      if (t >= off) x += y;
    }
    if (t == (int)blockIdx.x) sboff = (unsigned)(x - v);
    if (t == NBLK - 1) stotal = (unsigned)x;
  }
  __syncthreads();
  const int i = blockIdx.x * 1024 + t;
  if (i < N_NODES){
    int rp = rowptr[i] + (int)sboff;
    rowptr[i] = rp;
    int r = i / RANGE, off = i % RANGE;
    unsigned* p = part + ((size_t)r * NS) * RANGE + off;
    unsigned run = (unsigned)rp;
    #pragma unroll 8
    for (int s = 0; s < NS; ++s){
      unsigned c = p[(size_t)s * RANGE];
      p[(size_t)s * RANGE] = run;
      run += c;
    }
  } else if (i == N_NODES) rowptr[i] = (int)stotal;
}

// ---------------- scatter edges into CSR slots (LDS cursor atomics) ----------------
// grid = (NS, NRANGE)
__global__ __launch_bounds__(1024) void k_scatter_lds(const int* __restrict__ src,
                                                      const int* __restrict__ dst,
                                                      const unsigned* __restrict__ part,
                                                      int* __restrict__ esrc){
  __shared__ unsigned cur[RANGE];
  const int s = blockIdx.x, r = blockIdx.y;
  const int lo = r * RANGE;
  const unsigned* p = part + ((size_t)r * NS + s) * RANGE;
  for (int i = threadIdx.x; i < RANGE; i += 1024) cur[i] = p[i];
  __syncthreads();
  const int e0 = s * SLICE;
  for (int e = e0 + threadIdx.x; e < e0 + SLICE; e += 1024){
    int v = dst[e] - lo;
    if ((unsigned)v < RANGE){
      unsigned pos = atomicAdd(&cur[v], 1u);          // LDS atomic
      esrc[pos] = src[e];
    }
  }
}

// ---------------- MFMA GEMM: out[r][c] = bf16( onorm[r] * sum_k X[r][k] * W[k][c] ) ----------------
// X: bf16 [XPAD][128] or fp32 [N][128] (IN_F32: converted in-register, row clamped).
// Wt: bf16 [CT*16][128] (c-major). Block = 4 waves x 64 rows.
template<int CT, int WCOUT, int OUTC, bool IN_F32>
__global__ __launch_bounds__(256) void k_gemm_mfma(const void* __restrict__ xin,
                                                   const unsigned short* __restrict__ wt,
                                                   const float* __restrict__ onorm,
                                                   unsigned short* __restrict__ outb){
  __shared__ unsigned short Wl[CT * 16][136];
  const int t = threadIdx.x;
  const int lane = t & 63;
  const int w = t >> 6;
  const int ln15 = lane & 15;
  const int quad = lane >> 4;

  {
    const uint4* w4 = (const uint4*)wt;      // 16 uint4 per 128-bf16 row
    #pragma unroll
    for (int i = 0; i < CT; ++i){
      int idx = t + i * 256;
      int row = idx >> 4, q = idx & 15;
      *(uint4*)&Wl[row][q * 8] = w4[idx];
    }
  }
  __syncthreads();

  f32x4 acc[CT];
  #pragma unroll
  for (int ct = 0; ct < CT; ++ct) acc[ct] = (f32x4){0.f, 0.f, 0.f, 0.f};

  const int xr = min(blockIdx.x * 64 + w * 16 + ln15, N_NODES - 1);  // clamp: padded rows unused
  #pragma unroll
  for (int kp = 0; kp < 4; ++kp){
    bf16x8 a;
    if (IN_F32){
      const float4* x4 = (const float4*)xin + (size_t)xr * 32;
      float4 p0 = x4[kp * 8 + quad * 2];
      float4 p1 = x4[kp * 8 + quad * 2 + 1];
      union { bf16x8 v; unsigned u[4]; } ua;
      ua.u[0] = pkbf(p0.x, p0.y); ua.u[1] = pkbf(p0.z, p0.w);
      ua.u[2] = pkbf(p1.x, p1.y); ua.u[3] = pkbf(p1.z, p1.w);
      a = ua.v;
    } else {
      const unsigned short* xrow = (const unsigned short*)xin + (size_t)xr * 128;
      a = *(const bf16x8*)(xrow + kp * 32 + quad * 8);
    }
    #pragma unroll
    for (int ct = 0; ct < CT; ++ct){
      bf16x8 b = *(const bf16x8*)&Wl[ct * 16 + ln15][kp * 32 + quad * 8];
      acc[ct] = __builtin_amdgcn_mfma_f32_16x16x32_bf16(a, b, acc[ct], 0, 0, 0);
    }
  }

  // epilogue: C/D layout col=lane&15, row=quad*4+reg
  const int rowbase = blockIdx.x * 64 + w * 16 + quad * 4;
  float o[4];
  #pragma unroll
  for (int j = 0; j < 4; ++j){
    int r = rowbase + j;
    o[j] = (r < N_NODES) ? onorm[r] : 0.f;
  }
  #pragma unroll
  for (int ct = 0; ct < CT; ++ct){
    int col = ct * 16 + ln15;
    if (WCOUT < CT * 16 && col >= WCOUT) continue;
    #pragma unroll
    for (int j = 0; j < 4; ++j){
      int r = rowbase + j;
      if (r < N_NODES)
        outb[(size_t)r * OUTC + col] = bf1(acc[ct][j] * o[j]);
    }
  }
}

// ---------------- wave-per-node bf16 gather-aggregate (128-wide) ----------------
// htmp rows are 128 bf16 (64 u32); lane l owns cols {2l, 2l+1}.
template<bool OUTBF>
__global__ __launch_bounds__(256) void k_agg(const unsigned* __restrict__ htmp,
                                             const int* __restrict__ rowptr,
                                             const int* __restrict__ esrc,
                                             const float* __restrict__ inorm,
                                             const float* __restrict__ bias,
                                             void* __restrict__ outv){
  const int wave = threadIdx.x >> 6;
  const int lane = threadIdx.x & 63;
  const int node = blockIdx.x * 4 + wave;
  if (node >= N_NODES) return;
  const int start = rowptr[node], end = rowptr[node + 1];
  float aL[4] = {0.f, 0.f, 0.f, 0.f};
  float aH[4] = {0.f, 0.f, 0.f, 0.f};
  for (int e0 = start; e0 < end; e0 += 64){
    const int n = min(64, end - e0);
    int el = (lane < n) ? esrc[e0 + lane] : 0;
    int j = 0;
    for (; j + 8 <= n; j += 8){
      int ss[8];
      #pragma unroll
      for (int q = 0; q < 8; ++q) ss[q] = __shfl(el, j + q);
      unsigned uu[8];
      #pragma unroll
      for (int q = 0; q < 8; ++q) uu[q] = htmp[(size_t)ss[q] * 64 + lane];
      #pragma unroll
      for (int q = 0; q < 8; ++q){ aL[q & 3] += bflo(uu[q]); aH[q & 3] += bfhi(uu[q]); }
    }
    for (; j + 4 <= n; j += 4){
      int ss[4];
      #pragma unroll
      for (int q = 0; q < 4; ++q) ss[q] = __shfl(el, j + q);
      unsigned uu[4];
      #pragma unroll
      for (int q = 0; q < 4; ++q) uu[q] = htmp[(size_t)ss[q] * 64 + lane];
      #pragma unroll
      for (int q = 0; q < 4; ++q){ aL[q] += bflo(uu[q]); aH[q] += bfhi(uu[q]); }
    }
    for (; j < n; ++j){
      int s0 = __shfl(el, j);
      unsigned u0 = htmp[(size_t)s0 * 64 + lane];
      aL[0] += bflo(u0); aH[0] += bfhi(u0);
    }
  }
  float sc = inorm[node];
  float y0 = ((aL[0] + aL[1]) + (aL[2] + aL[3])) * sc + bias[2 * lane];
  float y1 = ((aH[0] + aH[1]) + (aH[2] + aH[3])) * sc + bias[2 * lane + 1];
  y0 = fmaxf(y0, 0.f); y1 = fmaxf(y1, 0.f);
  if (OUTBF){
    ((unsigned*)outv)[(size_t)node * 64 + lane] = pkbf(y0, y1);
  } else {
    float2 v; v.x = y0; v.y = y1;
    *(float2*)&((float*)outv)[(size_t)node * 128 + 2 * lane] = v;
  }
}

// ---------------- packed final aggregate: 3 nodes per wave (20 lanes each, 40-wide rows) ----------------
// htmp rows are 40 bf16 = 20 u32; sub-lane sl owns cols {2sl, 2sl+1}.
__global__ __launch_bounds__(256) void k_agg3(const unsigned* __restrict__ htmp,
                                              const int* __restrict__ rowptr,
                                              const int* __restrict__ esrc,
                                              const float* __restrict__ inorm,
                                              const float* __restrict__ bias,
                                              float* __restrict__ outf){
  const int wave = threadIdx.x >> 6;
  const int lane = threadIdx.x & 63;
  const int sg = lane / 20;               // subgroup 0..2 (3 = idle lanes 60-63)
  const int sl = lane % 20;
  const int node = blockIdx.x * 12 + wave * 3 + sg;
  const bool act = (sg < 3) && (node < N_NODES);
  const int start = act ? rowptr[node] : 0;
  const int end   = act ? rowptr[node + 1] : 0;
  float aL[4] = {0.f, 0.f, 0.f, 0.f};
  float aH[4] = {0.f, 0.f, 0.f, 0.f};
  for (int e0 = start; e0 < end; e0 += 20){
    const int n = min(20, end - e0);
    int el = (sl < n) ? esrc[e0 + sl] : 0;
    int j = 0;
    for (; j + 4 <= n; j += 4){
      int ss[4];
      #pragma unroll
      for (int q = 0; q < 4; ++q) ss[q] = __shfl(el, sg * 20 + j + q);
      unsigned uu[4];
      #pragma unroll
      for (int q = 0; q < 4; ++q) uu[q] = htmp[(size_t)ss[q] * 20 + sl];
      #pragma unroll
      for (int q = 0; q < 4; ++q){ aL[q] += bflo(uu[q]); aH[q] += bfhi(uu[q]); }
    }
    for (; j < n; ++j){
      int s0 = __shfl(el, sg * 20 + j);
      unsigned u0 = htmp[(size_t)s0 * 20 + sl];
      aL[0] += bflo(u0); aH[0] += bfhi(u0);
    }
  }
  if (act){
    float sc = inorm[node];
    float y0 = ((aL[0] + aL[1]) + (aL[2] + aL[3])) * sc + bias[2 * sl];
    float y1 = ((aH[0] + aH[1]) + (aH[2] + aH[3])) * sc + bias[2 * sl + 1];
    float2 v; v.x = y0; v.y = y1;
    *(float2*)&outf[(size_t)node * 40 + 2 * sl] = v;
  }
}

// ---------------- launch ----------------
extern "C" void kernel_launch(void* const* d_in, const int* in_sizes, int n_in,
                              void* d_out, int out_size, void* d_ws, size_t ws_size,
                              hipStream_t stream){
  const float* feat = (const float*)d_in[0];
  const float* W1   = (const float*)d_in[1];
  const float* b1   = (const float*)d_in[2];
  const float* W2   = (const float*)d_in[3];
  const float* b2   = (const float*)d_in[4];
  const float* W3   = (const float*)d_in[5];
  const float* b3   = (const float*)d_in[6];
  const int* src = (const int*)d_in[7];
  const int* dst = (const int*)d_in[8];
  float* out = (float*)d_out;

  char* ws = (char*)d_ws;
  float*    onorm   = (float*)   (ws + OFF_ONORM);
  float*    inorm   = (float*)   (ws + OFF_INORM);
  int*      rowptr  = (int*)     (ws + OFF_ROWPTR);
  unsigned* bsum    = (unsigned*)(ws + OFF_BSUM);
  unsigned* wt1     = (unsigned*)(ws + OFF_WT1);
  unsigned* wt2     = (unsigned*)(ws + OFF_WT2);
  unsigned* wt3     = (unsigned*)(ws + OFF_WT3);
  int*      esrc    = (int*)     (ws + OFF_ESRC);
  unsigned short* htmp = (unsigned short*)(ws + OFF_HTMP);
  unsigned short* xbuf = (unsigned short*)(ws + OFF_XBUF);
  unsigned* part    = (unsigned*)(ws + OFF_PART);   // aliases htmp (dead before GEMM1)

  // ---- CSR build (LDS atomics only) + folded weight prep ----
  k_hist_lds    <<<dim3(NS, NRANGE, 2), 1024, 0, stream>>>(src, dst, part,
                                                           W1, W2, W3, wt1, wt2, wt3);
  k_scan1       <<<NBLK, 1024, 0, stream>>>(part, rowptr, bsum, inorm, onorm);
  k_scan3       <<<NBLK, 1024, 0, stream>>>(rowptr, bsum, part);
  k_scatter_lds <<<dim3(NS, NRANGE), 1024, 0, stream>>>(src, dst, part, esrc);

  const int GB = XPAD / 64;            // 782
  const int AB = (N_NODES + 3) / 4;
  // layer 1 (fp32 feat read directly, converted in-register)
  k_gemm_mfma<8, 128, 128, true ><<<GB, 256, 0, stream>>>(feat, (unsigned short*)wt1, onorm, htmp);
  k_agg<true ><<<AB, 256, 0, stream>>>((unsigned*)htmp, rowptr, esrc, inorm, b1, xbuf);
  // layer 2
  k_gemm_mfma<8, 128, 128, false><<<GB, 256, 0, stream>>>(xbuf, (unsigned short*)wt2, onorm, htmp);
  k_agg<true ><<<AB, 256, 0, stream>>>((unsigned*)htmp, rowptr, esrc, inorm, b2, xbuf);
  // layer 3 (40 real cols, 64 computed)
  k_gemm_mfma<4, 40, 40, false><<<GB, 256, 0, stream>>>(xbuf, (unsigned short*)wt3, onorm, htmp);
  k_agg3<<<(N_NODES + 11) / 12, 256, 0, stream>>>((unsigned*)htmp, rowptr, esrc, inorm, b3, out);
}